// Round 13
// baseline (275.052 us; speedup 1.0000x reference)
//
#include <hip/hip_runtime.h>
#include <math.h>

typedef __bf16 bf16_t;
typedef bf16_t bf16x8 __attribute__((ext_vector_type(8)));
typedef bf16_t bf16x4 __attribute__((ext_vector_type(4)));
typedef float floatx4 __attribute__((ext_vector_type(4)));
typedef short short4v __attribute__((ext_vector_type(4)));

#define MFMA16(a, b, c) __builtin_amdgcn_mfma_f32_16x16x32_bf16((a), (b), (c), 0, 0, 0)

#if __has_builtin(__builtin_amdgcn_exp2f)
#define PEXP(x) __builtin_amdgcn_exp2f(x)
#define SCORE_SCALE (0.125f * 1.4426950408889634f)   // fold log2e into Q scale
#else
#define PEXP(x) __expf(x)
#define SCORE_SCALE 0.125f
#endif

#if __has_builtin(__builtin_amdgcn_mfma_f32_16x16x16bf16_1k)
#define HAVE_MFMA_K16 1
__device__ __forceinline__ floatx4 mfma_k16(bf16x4 a, bf16x4 b, floatx4 c)
{
    union { bf16x4 v; short4v s; } ua, ub;
    ua.v = a; ub.v = b;
    return __builtin_amdgcn_mfma_f32_16x16x16bf16_1k(ua.s, ub.s, c, 0, 0, 0);
}
#endif

union PU { unsigned u[2]; bf16x4 v; };
union BU { unsigned u[4]; bf16x8 v; };

// global -> LDS direct copy, 16 B per lane (wave-uniform LDS base + lane*16).
__device__ __forceinline__ void gld16(const void* g, void* lds)
{
    __builtin_amdgcn_global_load_lds(
        reinterpret_cast<const __attribute__((address_space(1))) void*>(
            reinterpret_cast<uintptr_t>(g)),
        reinterpret_cast<__attribute__((address_space(3))) void*>(
            (unsigned int)reinterpret_cast<uintptr_t>(lds)),
        16, 0, 0);
}

// ---------------------------------------------------------------------------
// 128x128-tile GEMM, m97-EXACT single-buffer structure + XCD swizzle (T1).
// C[M,N]=A[M,K]@Bt[N,K]^T. 256 thr (4 waves 2x2), BK=64, LDS = 32 KB static
// (ONE buffer) -> with __launch_bounds__(256,3): 3 blocks/CU, 12 waves/CU.
// r10->r12 showed occupancy is the lever (1/CU 299 -> 2/CU 288 -> +swz 274.7);
// m97/m114: single-buffer + __syncthreads (compiler drains vmcnt before
// s_barrier) at ~3 blocks/CU beats explicit double-buffering (m99/m100
// neutral) because inter-block wave overlap absorbs the drain stall.
// Per K-tile: {__syncthreads; stage 8 gld16 into SAME buffer; __syncthreads;
// 16 ds_read_b128; setprio 32 MFMA}. XOR-swizzled LDS throughout.
// ---------------------------------------------------------------------------
__device__ __forceinline__ void stage128(
    const bf16_t* __restrict__ g, int K, int r0, int k0,
    bf16_t* lds, int tid, int wave)
{
    #pragma unroll
    for (int i = 0; i < 4; ++i) {
        int c = i * 256 + tid, r = c >> 3, s = c & 7;
        gld16(g + (size_t)(r0 + r) * K + k0 + ((s ^ (r & 7)) << 3),
              lds + (size_t)(i * 256 + wave * 64) * 8);
    }
}

template <typename TC>
__device__ __forceinline__ void gemm128_body(
    const bf16_t* __restrict__ A, const bf16_t* __restrict__ Bt,
    TC* __restrict__ C, int row0, int col0, int N, int K,
    bf16_t* As, bf16_t* Bs)
{
    const int tid  = threadIdx.x;
    const int wave = tid >> 6, lane = tid & 63;
    const int quad = lane >> 4, l16 = lane & 15;
    const int wm = (wave >> 1) * 64;
    const int wn = (wave & 1) * 64;

    const int ntile = K >> 6;

    floatx4 acc[4][4] = {};

    #pragma unroll 1
    for (int u = 0; u < ntile; ++u) {
        __syncthreads();            // prev iter's LDS reads retired
        stage128(A, K, row0, u << 6, As, tid, wave);
        stage128(Bt, K, col0, u << 6, Bs, tid, wave);
        __syncthreads();            // staged data landed (vmcnt drained)

        bf16x8 af[4][2], bfr[4][2];
        #pragma unroll
        for (int mt = 0; mt < 4; ++mt)
            #pragma unroll
            for (int kh = 0; kh < 2; ++kh) {
                int ar = wm + mt * 16 + l16;
                af[mt][kh] = *(const bf16x8*)&As[ar * 64 +
                    (((kh * 4 + quad) ^ (ar & 7)) << 3)];
            }
        #pragma unroll
        for (int nt = 0; nt < 4; ++nt)
            #pragma unroll
            for (int kh = 0; kh < 2; ++kh) {
                int br = wn + nt * 16 + l16;
                bfr[nt][kh] = *(const bf16x8*)&Bs[br * 64 +
                    (((kh * 4 + quad) ^ (br & 7)) << 3)];
            }

        __builtin_amdgcn_s_setprio(1);
        #pragma unroll
        for (int kh = 0; kh < 2; ++kh)
            #pragma unroll
            for (int mt = 0; mt < 4; ++mt)
                #pragma unroll
                for (int nt = 0; nt < 4; ++nt)
                    acc[mt][nt] = MFMA16(af[mt][kh], bfr[nt][kh], acc[mt][nt]);
        __builtin_amdgcn_s_setprio(0);
    }

    #pragma unroll
    for (int mt = 0; mt < 4; ++mt)
        #pragma unroll
        for (int nt = 0; nt < 4; ++nt)
            #pragma unroll
            for (int r = 0; r < 4; ++r)
                C[(size_t)(row0 + wm + mt * 16 + quad * 4 + r) * N
                  + col0 + wn + nt * 16 + l16] = (TC)acc[mt][nt][r];
}

// Fused Q+K+V projection. Flat grid 768 = 24 col-tiles x 32 row-tiles,
// XCD-swizzled: each XCD owns a 96-block chunk (24 x-tiles x 4 y-rows).
// x<16 -> Q, x<20 -> K, else V.
__global__ __launch_bounds__(256, 3) void gemm128_qkv(
    const bf16_t* __restrict__ A, const bf16_t* __restrict__ BtQ,
    const bf16_t* __restrict__ BtK, const bf16_t* __restrict__ BtV,
    bf16_t* __restrict__ CQ, bf16_t* __restrict__ CK, bf16_t* __restrict__ CV)
{
    __shared__ alignas(16) bf16_t As[128 * 64];
    __shared__ alignas(16) bf16_t Bs[128 * 64];
    const int bid = blockIdx.x;
    const int l = (bid & 7) * 96 + (bid >> 3);   // bijective (768 = 8*96)
    const int x = l % 24;
    const int y = l / 24;
    const bf16_t* Bt; bf16_t* C; int N, col0;
    if (x < 16)      { Bt = BtQ; C = CQ; N = 2048; col0 = x * 128; }
    else if (x < 20) { Bt = BtK; C = CK; N = 512;  col0 = (x - 16) * 128; }
    else             { Bt = BtV; C = CV; N = 512;  col0 = (x - 20) * 128; }
    gemm128_body<bf16_t>(A, Bt, C, y * 128, col0, N, 2048, As, Bs);
}

// Output projection: flat 512 = 16 col-tiles x 32 row-tiles, XCD-swizzled
// (64-block chunk = 16 x-tiles x 4 y-rows). fp32 out.
__global__ __launch_bounds__(256, 3) void gemm128_out(
    const bf16_t* __restrict__ A, const bf16_t* __restrict__ Bt,
    float* __restrict__ C)
{
    __shared__ alignas(16) bf16_t As[128 * 64];
    __shared__ alignas(16) bf16_t Bs[128 * 64];
    const int bid = blockIdx.x;
    const int l = (bid & 7) * 64 + (bid >> 3);   // bijective (512 = 8*64)
    const int x = l & 15;
    const int y = l >> 4;
    gemm128_body<float>(A, Bt, C, y * 128, x * 128, 2048, 2048, As, Bs);
}

// ---------------------------------------------------------------------------
// Fused prep: x->bf16 conversion + Wq/Wk/Wv fp32->bf16 transposes.
// grid: [0,8192) conv, [8192,12288) Wq, [12288,13312) Wk, [13312,14336) Wv
// ---------------------------------------------------------------------------
__device__ __forceinline__ void transpose_body(
    const float* __restrict__ W, bf16_t* __restrict__ Wt, int K, int N,
    int bx, int by, float (*t)[33], int tid)
{
    int tx = tid & 31, ty = tid >> 5;
    #pragma unroll
    for (int i = 0; i < 32; i += 8)
        t[ty + i][tx] = W[(size_t)(by + ty + i) * N + bx + tx];
    __syncthreads();
    #pragma unroll
    for (int i = 0; i < 32; i += 8)
        Wt[(size_t)(bx + ty + i) * K + by + tx] = (bf16_t)t[tx][ty + i];
}

__global__ __launch_bounds__(256) void prep_all(
    const float* __restrict__ x, const float* __restrict__ Wq,
    const float* __restrict__ Wk, const float* __restrict__ Wv,
    bf16_t* __restrict__ xb, bf16_t* __restrict__ WqT,
    bf16_t* __restrict__ WkT, bf16_t* __restrict__ WvT)
{
    __shared__ float t[32][33];
    const int blk = blockIdx.x, tid = threadIdx.x;
    if (blk < 8192) {
        int i = blk * 256 + tid;
        float4 f = ((const float4*)x)[i];
        bf16x4 v = {(bf16_t)f.x, (bf16_t)f.y, (bf16_t)f.z, (bf16_t)f.w};
        ((bf16x4*)xb)[i] = v;
    } else if (blk < 12288) {
        int r = blk - 8192;
        transpose_body(Wq, WqT, 2048, 2048, (r & 63) * 32, (r >> 6) * 32, t, tid);
    } else if (blk < 13312) {
        int r = blk - 12288;
        transpose_body(Wk, WkT, 2048, 512, (r & 15) * 32, (r >> 4) * 32, t, tid);
    } else {
        int r = blk - 13312;
        transpose_body(Wv, WvT, 2048, 512, (r & 15) * 32, (r >> 4) * 32, t, tid);
    }
}

// ---------------------------------------------------------------------------
// Fused mid: RoPE(K) + V-transpose + Wo-transpose.
// grid: [0,4096) rope, [4096,6144) V^T, [6144,10240) Wo
// ---------------------------------------------------------------------------
__global__ __launch_bounds__(256) void mid_all(
    bf16_t* __restrict__ Kw, const bf16_t* __restrict__ Vw,
    bf16_t* __restrict__ VtG, const float* __restrict__ Wo,
    bf16_t* __restrict__ WoT)
{
    __shared__ float tf[32][33];
    __shared__ bf16_t tb[32][34];
    const int blk = blockIdx.x, tid = threadIdx.x;
    if (blk < 4096) {
        int idx = blk * 256 + tid;
        int i   = idx & 31;
        int h   = (idx >> 5) & 7;
        int row = idx >> 8;
        int pos = row & 2047;
        float invf = powf(10000.0f, -(float)i / 32.0f);
        float sv, cv;
        sincosf((float)pos * invf, &sv, &cv);
        size_t base = (size_t)row * 512 + (size_t)h * 64 + i;
        float a  = (float)Kw[base];
        float b2 = (float)Kw[base + 32];
        Kw[base]      = (bf16_t)(a * cv - b2 * sv);
        Kw[base + 32] = (bf16_t)(b2 * cv + a * sv);
    } else if (blk < 6144) {
        int r  = blk - 4096;
        int bz = r >> 10, r2 = r & 1023;
        int bx = (r2 & 15) * 32, by = (r2 >> 4) * 32;
        int tx = tid & 31, ty = tid >> 5;
        #pragma unroll
        for (int i = 0; i < 32; i += 8)
            tb[ty + i][tx] = Vw[((size_t)bz * 2048 + by + ty + i) * 512 + bx + tx];
        __syncthreads();
        #pragma unroll
        for (int i = 0; i < 32; i += 8)
            VtG[((size_t)bz * 512 + bx + ty + i) * 2048 + by + tx] = tb[tx][ty + i];
    } else {
        int r = blk - 6144;
        transpose_body(Wo, WoT, 2048, 2048, (r & 63) * 32, (r >> 6) * 32, tf, tid);
    }
}

// ---------------------------------------------------------------------------
// Causal GQA flash attention, GROUP-SHARED K/V + XCD-PINNED GROUPS,
// KVBLK=128 fat windows. (byte-identical to rounds 9-12 — 81.4-84.2 us)
// ---------------------------------------------------------------------------
__global__ __launch_bounds__(256, 2) void gqa_attn(
    const bf16_t* __restrict__ Q, const bf16_t* __restrict__ Kc,
    const bf16_t* __restrict__ Vt, bf16_t* __restrict__ AO)
{
    __shared__ alignas(16) bf16_t Ks[2][128 * 64];  // [buf][2x 64x64 swizzled]
    __shared__ alignas(16) bf16_t Vs[2][128 * 64];  // [buf][2x 64d x 64k swz]

    const int bid = blockIdx.x;
    const int l   = (bid & 7) * 64 + (bid >> 3);   // XCD-pinning remap
    const int g   = l >> 6;                        // kv-group == XCD
    const int b   = (l >> 5) & 1;
    const int x   = l & 31;

    const int tid  = threadIdx.x;
    const int wave = tid >> 6, lane = tid & 63;
    const int quad = lane >> 4, l16 = lane & 15;
    const int h = g * 4 + wave;                // each wave owns one head

    #pragma unroll 1
    for (int t = 0; t < 2; ++t) {
        const int qt = t ? x : (63 - x);       // 32-row tile idx, heavy first
        const int q0 = qt * 32;
        int qb[2];
        qb[0] = q0;
        qb[1] = q0 + 16;

        // Q as B-frag (Q^T): lane holds Q[qb+l16][kh*32+quad*8+j], RoPE+scale
        bf16x8 qf[2][2];
        #pragma unroll
        for (int mt = 0; mt < 2; ++mt) {
            int qrow = qb[mt] + l16;
            const bf16_t* qp = Q + (size_t)(b * 2048 + qrow) * 2048 + h * 64 + quad * 8;
            bf16x8 lo = *(const bf16x8*)qp;
            bf16x8 hi = *(const bf16x8*)(qp + 32);
            #pragma unroll
            for (int j = 0; j < 8; ++j) {
                int d = quad * 8 + j;
                float invf = powf(10000.0f, -(float)d / 32.0f);
                float sv, cv;
                sincosf((float)qrow * invf, &sv, &cv);
                float a = (float)lo[j], c2 = (float)hi[j];
                qf[mt][0][j] = (bf16_t)((a * cv - c2 * sv) * SCORE_SCALE);
                qf[mt][1][j] = (bf16_t)((c2 * cv + a * sv) * SCORE_SCALE);
            }
        }

        floatx4 o[2][4] = {};     // O^T: [mt][dt], rows d=quad*4+r, col q=l16
        floatx4 ls4[2] = {};      // lsum partials per q=l16 (4 chains)

        const int ktmax = qt >> 1;             // last valid 64-key tile
        const int nwin  = (ktmax >> 1) + 1;    // 128-key windows

        // stage window `win` (128 keys) into buffer dst: 4 K + 4 V rounds
        auto STAGE = [&](int win, int dst) {
            const int kbase = win * 128;
            #pragma unroll
            for (int i = 0; i < 4; ++i) {       // K rows kbase..kbase+127
                int c = i * 256 + tid, r = c >> 3, s = c & 7;
                int sw = (s ^ (r & 7)) << 3;
                gld16(Kc + (size_t)(b * 2048 + kbase + r) * 512 + g * 64 + sw,
                      &Ks[dst][(i * 256 + wave * 64) * 8]);
            }
            #pragma unroll
            for (int i = 0; i < 4; ++i) {       // V^T: d-rows x 2 key-halves
                int c = i * 256 + tid;
                int ci = c & 511, hw = c >> 9;
                int r = ci >> 3, s = ci & 7;
                int sw = (s ^ (r & 7)) << 3;
                gld16(Vt + (size_t)(b * 512 + g * 64 + r) * 2048
                         + kbase + hw * 64 + sw,
                      &Vs[dst][(i * 256 + wave * 64) * 8]);
            }
        };

        // prologue: buffers free (prev tile drained), prefetch window 0
        __asm__ volatile("s_waitcnt lgkmcnt(0)" ::: "memory");
        __builtin_amdgcn_s_barrier();
        STAGE(0, 0);

        #pragma unroll 1
        for (int win = 0; win < nwin; ++win) {
            const int cur = win & 1;
            if (win + 1 < nwin) {
                STAGE(win + 1, cur ^ 1);
                __asm__ volatile("s_waitcnt vmcnt(8)" ::: "memory");
            } else {
                __asm__ volatile("s_waitcnt vmcnt(0)" ::: "memory");
            }
            __builtin_amdgcn_s_barrier();   // buf[cur] fully landed

            #pragma unroll
            for (int hw = 0; hw < 2; ++hw) {
                const int kt = 2 * win + hw;
                if (kt <= ktmax) {
                    const bf16_t* Ksh = &Ks[cur][hw * 4096];
                    const bf16_t* Vsh = &Vs[cur][hw * 4096];

                    // S^T = K.Q^T
                    floatx4 st[2][4] = {};
                    __builtin_amdgcn_s_setprio(1);
                    #pragma unroll
                    for (int nt = 0; nt < 4; ++nt) {
                        int kr = nt * 16 + l16;
                        bf16x8 kf0 = *(const bf16x8*)&Ksh[kr * 64 + ((quad ^ (kr & 7)) << 3)];
                        bf16x8 kf1 = *(const bf16x8*)&Ksh[kr * 64 + (((4 + quad) ^ (kr & 7)) << 3)];
                        st[0][nt] = MFMA16(kf0, qf[0][0], st[0][nt]);
                        st[0][nt] = MFMA16(kf1, qf[0][1], st[0][nt]);
                        st[1][nt] = MFMA16(kf0, qf[1][0], st[1][nt]);
                        st[1][nt] = MFMA16(kf1, qf[1][1], st[1][nt]);
                    }
                    __builtin_amdgcn_s_setprio(0);

                    // exp2 + causal mask (diag tile only) + lsum + pack P^T
                    PU pk[2][4];
                    const bool diag = (kt == ktmax);
                    #pragma unroll
                    for (int mt = 0; mt < 2; ++mt) {
                        const int qa = qb[mt] + l16;
                        #pragma unroll
                        for (int nt = 0; nt < 4; ++nt) {
                            float pv[4];
                            #pragma unroll
                            for (int r = 0; r < 4; ++r) {
                                float e = PEXP(st[mt][nt][r]);
                                if (diag) {
                                    int ka = kt * 64 + nt * 16 + quad * 4 + r;
                                    if (ka > qa) e = 0.f;
                                }
                                ls4[mt][r] += e;
                                pv[r] = e;
                            }
                            pk[mt][nt].v = bf16x4{(bf16_t)pv[0], (bf16_t)pv[1],
                                                  (bf16_t)pv[2], (bf16_t)pv[3]};
                        }
                    }

#ifdef HAVE_MFMA_K16
                    // O^T += V^T.P^T  (P^T straight from registers)
                    __builtin_amdgcn_s_setprio(1);
                    #pragma unroll
                    for (int nt = 0; nt < 4; ++nt)
                        #pragma unroll
                        for (int dt = 0; dt < 4; ++dt) {
                            int vr = dt * 16 + l16;
                            int slot = ((nt << 1) | (quad >> 1)) ^ (vr & 7);
                            bf16x4 va = *(const bf16x4*)&Vsh[vr * 64 + (slot << 3)
                                                             + ((quad & 1) << 2)];
                            o[0][dt] = mfma_k16(va, pk[0][nt].v, o[0][dt]);
                            o[1][dt] = mfma_k16(va, pk[1][nt].v, o[1][dt]);
                        }
                    __builtin_amdgcn_s_setprio(0);
#else
                    #pragma unroll
                    for (int H = 0; H < 2; ++H) {
                        BU bfv[2];
                        #pragma unroll
                        for (int mt = 0; mt < 2; ++mt) {
                            #pragma unroll
                            for (int j = 0; j < 4; ++j) {
                                int srcl = (((quad & 1) << 1) + (j >> 1)) * 16 + l16;
                                unsigned a0 = (unsigned)__shfl((int)pk[mt][2 * H].u[j & 1], srcl, 64);
                                unsigned a1 = (unsigned)__shfl((int)pk[mt][2 * H + 1].u[j & 1], srcl, 64);
                                bfv[mt].u[j] = (quad >> 1) ? a1 : a0;
                            }
                        }
                        #pragma unroll
                        for (int dt = 0; dt < 4; ++dt) {
                            int vr = dt * 16 + l16;
                            bf16x8 va = *(const bf16x8*)&Vsh[vr * 64
                                          + ((((H << 2) | quad) ^ (vr & 7)) << 3)];
                            o[0][dt] = MFMA16(va, bfv[0].v, o[0][dt]);
                            o[1][dt] = MFMA16(va, bfv[1].v, o[1][dt]);
                        }
                    }
#endif
                }
            }

            // reads of buf[cur] retired before anyone overwrites it
            __asm__ volatile("s_waitcnt lgkmcnt(0)" ::: "memory");
            __builtin_amdgcn_s_barrier();
        }

        // epilogue: finish lsum (sum 4 chains + quad reduce), divide, store
        #pragma unroll
        for (int mt = 0; mt < 2; ++mt) {
            float l2 = ls4[mt][0] + ls4[mt][1] + ls4[mt][2] + ls4[mt][3];
            l2 += __shfl_xor(l2, 16, 64);
            l2 += __shfl_xor(l2, 32, 64);
            float rc = 1.0f / l2;
            #pragma unroll
            for (int dt = 0; dt < 4; ++dt) {
                bf16x4 ov = {(bf16_t)(o[mt][dt][0] * rc), (bf16_t)(o[mt][dt][1] * rc),
                             (bf16_t)(o[mt][dt][2] * rc), (bf16_t)(o[mt][dt][3] * rc)};
                *(bf16x4*)&AO[(size_t)(b * 2048 + qb[mt] + l16) * 2048
                              + h * 64 + dt * 16 + quad * 4] = ov;
            }
        }
    }
}

// ---------------------------------------------------------------------------
extern "C" void kernel_launch(void* const* d_in, const int* in_sizes, int n_in,
                              void* d_out, int out_size, void* d_ws, size_t ws_size,
                              hipStream_t stream)
{
    const float* x  = (const float*)d_in[0];
    const float* Wq = (const float*)d_in[1];
    const float* Wk = (const float*)d_in[2];
    const float* Wv = (const float*)d_in[3];
    const float* Wo = (const float*)d_in[4];
    float* out = (float*)d_out;

    const size_t MB = 1024 * 1024;
    char* ws = (char*)d_ws;
    bf16_t* xb_AO = (bf16_t*)(ws);              // 16 MiB: xb, later AO
    bf16_t* WqoT  = (bf16_t*)(ws + 16 * MB);    //  8 MiB: Wq^T, later Wo^T
    bf16_t* WkT   = (bf16_t*)(ws + 24 * MB);    //  2 MiB
    bf16_t* WvT   = (bf16_t*)(ws + 26 * MB);    //  2 MiB
    bf16_t* Qw    = (bf16_t*)(ws + 28 * MB);    // 16 MiB
    bf16_t* Kw    = (bf16_t*)(ws + 44 * MB);    //  4 MiB
    bf16_t* Vw    = (bf16_t*)(ws + 48 * MB);    //  4 MiB
    bf16_t* VtG   = (bf16_t*)(ws + 52 * MB);    //  4 MiB

    // 1) prep: x->bf16, Wq/Wk/Wv -> transposed bf16
    prep_all<<<14336, 256, 0, stream>>>(x, Wq, Wk, Wv, xb_AO, WqoT, WkT, WvT);

    // 2) fused QKV projection (m97 single-buffer 128x128, flat 768, XCD-swz)
    gemm128_qkv<<<dim3(768), 256, 0, stream>>>(
        xb_AO, WqoT, WkT, WvT, Qw, Kw, Vw);

    // 3) RoPE(K) + V->V^T + Wo^T (Wo^T reuses Wq^T region, dead after QKV)
    mid_all<<<10240, 256, 0, stream>>>(Kw, Vw, VtG, Wo, WqoT);

    // 4) attention: group-shared K/V, XCD-pinned, 128-key fat windows
    gqa_attn<<<dim3(512), 256, 0, stream>>>(Qw, Kw, VtG, xb_AO);

    // 5) output projection (m97 single-buffer, flat 512, XCD-swz, fp32 out)
    gemm128_out<<<dim3(512), 256, 0, stream>>>(xb_AO, WqoT, out);
}